// Round 6
// baseline (88.170 us; speedup 1.0000x reference)
//
#include <hip/hip_runtime.h>

// FHE BSGS: out[b,s] = sum_{t=0..15} x[b,(s+2^t)&0xFFFF] * diag[t,s], rolled by 32768.
// Roll by S/2 on the 2^16 ring == store to column s ^ 0x8000 (coalesced).
//
// v12: single-variable A/B vs v11 -- NT stores REMOVED, everything else identical.
// Ledger: v8 (NT ld+st) 95.1 -> v9 (no NT) 91.8: removing NT = -3.3 us.
//         v10 (no NT)   82.9 -> v11 (NT st) 86.0: adding NT st = +3.1 us.
// Theory: NT stores bypass L2 and contend at HBM during the kernel; regular
// stores retire into L2 and write back lazily (out is scrubbed next iteration
// anyway). The v11 geometry/byte changes (164 MB, diag shared by 8 rows) are
// kept so this round cleanly attributes NT vs geometry:
//   NT poison    -> ~76-80 us (new best, byte cut pays at recovered rate)
//   geometry poison -> ~85-86 us persists -> revert to 1024-block shape next.

#define SLOTS 65536
#define MASK  65535
#define NBR   8       // batch rows per block
#define TILEW 1024    // columns per block
#define STRIPW 2048   // TILEW + 1024 lookahead (covers shifts 1..1024)

__global__ __launch_bounds__(512) void bsgs_kernel(
    const float* __restrict__ x,
    const float* __restrict__ diag,
    float* __restrict__ out)
{
    __shared__ float  sstrip[NBR][STRIPW];     // 64 KB: x[row][(J+i)&MASK], i<2048
    __shared__ float4 sdiag[16][TILEW / 4];    // 64 KB: diag[t][J + c4*4 .. +3]

    const int bid  = blockIdx.x;       // 0..511
    const int y    = bid & 7;          // batch group == XCD (bid%8 round-robin)
    const int xidx = bid >> 3;         // column tile 0..63
    const int tid  = threadIdx.x;      // 0..511
    const int c4   = tid & 255;        // f4-column within tile
    const int rp   = tid >> 8;         // 0/1 -> this thread owns rows rp*4..rp*4+3
    const int J    = xidx * TILEW;
    const int j    = J + c4 * 4;
    const int bg   = y * NBR;
    const int r0   = rp * 4;

    // (1) big shifts t=11..15 for this thread's 4 rows -- issued FIRST so the
    // HBM/L3 latency flies under the LDS staging and the barrier.
    float4 vd[4][5];
#pragma unroll
    for (int q = 0; q < 4; ++q) {
        const float* __restrict__ xr = x + (size_t)(bg + r0 + q) * SLOTS;
#pragma unroll
        for (int t = 11; t < 16; ++t)
            vd[q][t - 11] = *(const float4*)(xr + ((j + (1 << t)) & MASK));
    }

    // (2) stage diag: thread handles t = 2*tt + rp, its own c4. Coalesced, once
    // per block -> shared by all 8 rows.
#pragma unroll
    for (int tt = 0; tt < 8; ++tt) {
        const int t = tt * 2 + rp;
        sdiag[t][c4] = *(const float4*)(diag + t * SLOTS + J + c4 * 4);
    }

    // (3) stage strips: 1 f4 per (thread, row); 512 threads cover 2048 floats.
#pragma unroll
    for (int r = 0; r < NBR; ++r) {
        const float* __restrict__ xr = x + (size_t)(bg + r) * SLOTS;
        *(float4*)(&sstrip[r][tid * 4]) =
            *(const float4*)(xr + ((J + tid * 4) & MASK));
    }
    __syncthreads();   // the only barrier

    float4 acc[4];
#pragma unroll
    for (int q = 0; q < 4; ++q) acc[q] = make_float4(0.f, 0.f, 0.f, 0.f);

    // t=0..2 (shifts 1,2,4) from per-row v0/w4 slides.
    {
        float4 v0[4], w4[4];
#pragma unroll
        for (int q = 0; q < 4; ++q) {
            const float* sp = &sstrip[r0 + q][c4 * 4];
            v0[q] = *(const float4*)(sp);
            w4[q] = *(const float4*)(sp + 4);
        }
        const float4 d0 = sdiag[0][c4];
        const float4 d1 = sdiag[1][c4];
        const float4 d2 = sdiag[2][c4];
#pragma unroll
        for (int q = 0; q < 4; ++q) {
            acc[q].x += v0[q].y * d0.x + v0[q].z * d1.x + w4[q].x * d2.x;
            acc[q].y += v0[q].z * d0.y + v0[q].w * d1.y + w4[q].y * d2.y;
            acc[q].z += v0[q].w * d0.z + w4[q].x * d1.z + w4[q].z * d2.z;
            acc[q].w += w4[q].x * d0.w + w4[q].y * d1.w + w4[q].w * d2.w;
        }
    }

    // t=3..10 (shifts 8..1024): aligned conflict-free b128 strip reads.
#pragma unroll
    for (int t = 3; t <= 10; ++t) {
        const float4 d = sdiag[t][c4];
#pragma unroll
        for (int q = 0; q < 4; ++q) {
            const float4 v = *(const float4*)(&sstrip[r0 + q][c4 * 4 + (1 << t)]);
            acc[q].x += v.x * d.x; acc[q].y += v.y * d.y;
            acc[q].z += v.z * d.z; acc[q].w += v.w * d.w;
        }
    }

    // t=11..15: the pre-issued global loads.
#pragma unroll
    for (int t = 11; t < 16; ++t) {
        const float4 d = sdiag[t][c4];
#pragma unroll
        for (int q = 0; q < 4; ++q) {
            const float4 v = vd[q][t - 11];
            acc[q].x += v.x * d.x; acc[q].y += v.y * d.y;
            acc[q].z += v.z * d.z; acc[q].w += v.w * d.w;
        }
    }

    // roll by 32768 == XOR top column bit; stores stay coalesced.
    // Regular stores: retire into L2, lazy writeback (out is scrubbed next
    // iteration anyway; NT measured +3 us twice -- v8 vs v9, v10 vs v11).
#pragma unroll
    for (int q = 0; q < 4; ++q)
        *(float4*)(out + (size_t)(bg + r0 + q) * SLOTS + (j ^ 32768)) = acc[q];
}

extern "C" void kernel_launch(void* const* d_in, const int* in_sizes, int n_in,
                              void* d_out, int out_size, void* d_ws, size_t ws_size,
                              hipStream_t stream) {
    const float* x    = (const float*)d_in[0];   // (64, 65536) fp32
    const float* diag = (const float*)d_in[1];   // (16, 65536) fp32
    float* out        = (float*)d_out;           // (64, 65536) fp32
    // d_in[2] = stride (1), d_in[3] = reps (1) -- compile-time constants here.

    bsgs_kernel<<<dim3(512), dim3(512), 0, stream>>>(x, diag, out);
}

// Round 7
// 85.496 us; speedup vs baseline: 1.0313x; 1.0313x over previous
//
#include <hip/hip_runtime.h>

// FHE BSGS: out[b,s] = sum_{t=0..15} x[b,(s+2^t)&0xFFFF] * diag[t,s], rolled by 32768.
// Roll by S/2 on the 2^16 ring == store to column s ^ 0x8000 (coalesced).
//
// v13: one-batch-group-per-XCD at the PROVEN 1024-block x 256-thread geometry.
// Ledger: 512-block shapes regress (v8/v9/v11/v12: 95/92/86/88); 1024x256 shapes
// cluster at 83-86; byte cuts alone move <= noise. Model: kernel ~40us serves
// ~200MB at flat ~5TB/s -- L2 captures no x-reuse because diag (4.2MB/XCD, 2x)
// + two groups' x (2MB) thrash the 4MB L2.
// v13: grid = 8 groups x 128 tiles (TILEW=512, NBR=8) = 1024 blocks, y = bid&7
// == XCD:
//   - diag single-touch per XCD (33.5 MB chip-wide, was 67); no double scrub.
//   - each XCD owns ONE group: 8 x-rows = 2 MB, L2-resident; ALL big-shift
//     windows (t=10..15) are same-row, same-XCD -> ~100MB of requests become
//     L2-hit candidates at 34.5 TB/s.
//   - total requests 201 -> 184.5 MB at unchanged block/thread shape.
// LDS 64 KB (strip 8x1024 floats = 32K + diag 16x128 f4 = 32K) -> 2 blocks/CU.
// Strip lookahead 512 covers t<=9; t=10..15 are global loads (6 f4/row).

#define SLOTS  65536
#define MASK   65535
#define NBR    8       // batch rows per block (= rows per XCD group)
#define TILEW  512     // columns per tile; 128 tiles per row
#define STRIPF 1024    // strip floats per row: TILEW + 512 lookahead (t<=9)

__global__ __launch_bounds__(256) void bsgs_kernel(
    const float* __restrict__ x,
    const float* __restrict__ diag,
    float* __restrict__ out)
{
    __shared__ float  sstrip[NBR][STRIPF];    // 32 KB
    __shared__ float4 sdiag[16][TILEW / 4];   // 32 KB

    const int bid  = blockIdx.x;       // 0..1023
    const int y    = bid & 7;          // batch group == XCD (bid%8 round-robin)
    const int xidx = bid >> 3;         // column tile 0..127
    const int tid  = threadIdx.x;      // 0..255
    const int c4   = tid & 127;        // f4-column within tile
    const int rp   = tid >> 7;         // 0/1 -> owns rows rp*4 .. rp*4+3
    const int r0   = rp * 4;
    const int J    = xidx * TILEW;
    const int j    = J + c4 * 4;
    const int bg   = y * NBR;

    // Stage diag: each thread 8 t's at its c4; coalesced 2 KB per (t, half).
#pragma unroll
    for (int tt = 0; tt < 8; ++tt) {
        const int t = tt * 2 + rp;
        sdiag[t][c4] = *(const float4*)(diag + t * SLOTS + J + c4 * 4);
    }

    // Stage strips: 1 f4 per thread per row (256 thr x 4 floats = 1024 floats).
#pragma unroll
    for (int r = 0; r < NBR; ++r) {
        const float* __restrict__ xr = x + (size_t)(bg + r) * SLOTS;
        *(float4*)(&sstrip[r][tid * 4]) =
            *(const float4*)(xr + ((J + tid * 4) & MASK));
    }
    __syncthreads();   // the only barrier

    // Big shifts t=10..15 for the 4 owned rows: global loads (L2-local now).
    float4 vd[4][6];
#pragma unroll
    for (int q = 0; q < 4; ++q) {
        const float* __restrict__ xr = x + (size_t)(bg + r0 + q) * SLOTS;
#pragma unroll
        for (int t = 10; t < 16; ++t)
            vd[q][t - 10] = *(const float4*)(xr + ((j + (1 << t)) & MASK));
    }

    float4 acc[4];
#pragma unroll
    for (int q = 0; q < 4; ++q) acc[q] = make_float4(0.f, 0.f, 0.f, 0.f);

#pragma unroll
    for (int q = 0; q < 4; ++q) {
        const float* sp = &sstrip[r0 + q][c4 * 4];
        const float4 v0 = *(const float4*)(sp);      // shift 0 base
        const float4 w4 = *(const float4*)(sp + 4);  // shift 4 (t=2; t=0,1 tails)

        // t=0 (shift 1): (v0.y, v0.z, v0.w, w4.x); t=1 (shift 2): (v0.z, v0.w, w4.x, w4.y)
        {
            const float4 d0 = sdiag[0][c4];
            const float4 d1 = sdiag[1][c4];
            const float4 d2 = sdiag[2][c4];
            acc[q].x += v0.y * d0.x + v0.z * d1.x + w4.x * d2.x;
            acc[q].y += v0.z * d0.y + v0.w * d1.y + w4.y * d2.y;
            acc[q].z += v0.w * d0.z + w4.x * d1.z + w4.z * d2.z;
            acc[q].w += w4.x * d0.w + w4.y * d1.w + w4.w * d2.w;
        }

        // t=3..9 (shifts 8..512): aligned conflict-free b128 strip reads.
#pragma unroll
        for (int t = 3; t <= 9; ++t) {
            const float4 v = *(const float4*)(sp + (1 << t));
            const float4 d = sdiag[t][c4];
            acc[q].x += v.x * d.x; acc[q].y += v.y * d.y;
            acc[q].z += v.z * d.z; acc[q].w += v.w * d.w;
        }

        // t=10..15 (shifts 1024..32768): the pre-issued global loads.
#pragma unroll
        for (int t = 10; t < 16; ++t) {
            const float4 v = vd[q][t - 10];
            const float4 d = sdiag[t][c4];
            acc[q].x += v.x * d.x; acc[q].y += v.y * d.y;
            acc[q].z += v.z * d.z; acc[q].w += v.w * d.w;
        }
    }

    // roll by 32768 == XOR top column bit; stores stay coalesced.
#pragma unroll
    for (int q = 0; q < 4; ++q)
        *(float4*)(out + (size_t)(bg + r0 + q) * SLOTS + (j ^ 32768)) = acc[q];
}

extern "C" void kernel_launch(void* const* d_in, const int* in_sizes, int n_in,
                              void* d_out, int out_size, void* d_ws, size_t ws_size,
                              hipStream_t stream) {
    const float* x    = (const float*)d_in[0];   // (64, 65536) fp32
    const float* diag = (const float*)d_in[1];   // (16, 65536) fp32
    float* out        = (float*)d_out;           // (64, 65536) fp32
    // d_in[2] = stride (1), d_in[3] = reps (1) -- compile-time constants here.

    bsgs_kernel<<<dim3(1024), dim3(256), 0, stream>>>(x, diag, out);
}

// Round 8
// 82.066 us; speedup vs baseline: 1.0744x; 1.0418x over previous
//
#include <hip/hip_runtime.h>

// FHE BSGS: out[b,s] = sum_{t=0..15} x[b,(s+2^t)&0xFFFF] * diag[t,s], rolled by 32768.
// Roll by S/2 on the 2^16 ring == store to column s ^ 0x8000 (coalesced).
//
// v14 == v10 RESTORED (measured best: 82.9 us). Final-state kernel.
//
// Session conclusion (8 experiments, v6..v13):
//   dur ~= harness reset (~44 us, 268 MB cache scrub at 77% of HBM peak)
//        + kernel (~33 us: ~201 MB of requests at the flat ~6 TB/s L3/HBM
//          achievable rate) + ~5 us launch/latency.
//   Falsified levers: 2x occupancy (v7, null); request-byte cuts -15..-30%
//   (v10/v11/v13: sub-noise or negative -- x-pass count is pinned at 7 by the
//   lookahead identity 16.8*(1+L/T)+16.8*(15-log2 L) for all LDS-feasible
//   (T,L) at 1024 blocks); NBR=8 diag-sharing (forces T=512 or 512-block
//   geometry, both measured worse); NT hints (noise both ways); XCD pinning
//   (v13, null). 512-block shapes cost +3..+10 us consistently.
//   v10 sits within a few percent of the structural floor -> roofline.
//
// Structure: 1024 blocks x 256 thr, NB=4 rows/block, diag in registers,
// 8 KB/row LDS strip covers shifts 1..1024 (t=0..10) as conflict-free
// ds_read_b128; t=11..15 are 5 direct coalesced global passes; one barrier.

#define SLOTS 65536
#define MASK  65535
#define NB    4
#define STRIPW 2048

__global__ __launch_bounds__(256) void bsgs_kernel(
    const float* __restrict__ x,
    const float* __restrict__ diag,
    float* __restrict__ out)
{
    __shared__ float sstrip[NB][STRIPW];   // 32 KB

    const int bid  = blockIdx.x;          // 0..1023
    const int y    = bid & 15;            // batch group (group -> XCD y%8)
    const int xidx = bid >> 4;            // column tile 0..63
    const int tid  = threadIdx.x;
    const int J    = xidx * 1024;
    const int j    = J + tid * 4;         // column base (multiple of 4)
    const int bg   = y * NB;

    // diag[t, j..j+3], t=0..15 -- reused across NB batch rows (64 VGPR).
    float4 dreg[16];
#pragma unroll
    for (int t = 0; t < 16; ++t)
        dreg[t] = *(const float4*)(diag + t * SLOTS + j);

    // Stage all NB strips: x[row][(J+i)&MASK], i in [0,2048). 2 f4 per row per thread.
#pragma unroll
    for (int b = 0; b < NB; ++b) {
        const float* __restrict__ xr = x + (size_t)(bg + b) * SLOTS;
#pragma unroll
        for (int h = 0; h < 2; ++h) {
            const int i = tid * 4 + h * 1024;
            *(float4*)(&sstrip[b][i]) = *(const float4*)(xr + ((J + i) & MASK));
        }
    }
    __syncthreads();   // the only barrier

    float4 acc[NB];
#pragma unroll
    for (int b = 0; b < NB; ++b) acc[b] = make_float4(0.f, 0.f, 0.f, 0.f);

#pragma unroll
    for (int b = 0; b < NB; ++b) {
        const float* __restrict__ xr = x + (size_t)(bg + b) * SLOTS;

        // Big shifts t=11..15 (2048..32768): direct global loads, issued first.
        float4 vd[5];
#pragma unroll
        for (int t = 11; t < 16; ++t)
            vd[t - 11] = *(const float4*)(xr + ((j + (1 << t)) & MASK));

        // All windows for shifts <=1024 from the LDS strip (aligned b128 reads).
        const float* sp = &sstrip[b][tid * 4];
        const float4 v0 = *(const float4*)(sp);        // shift 0 (for t=0,1 slides)
        const float4 w4 = *(const float4*)(sp + 4);    // shift 4 (t=2; t=0,1 tail)

        // t=0 (shift 1): (v0.y, v0.z, v0.w, w4.x); t=1 (shift 2): (v0.z, v0.w, w4.x, w4.y)
        acc[b].x += v0.y * dreg[0].x + v0.z * dreg[1].x;
        acc[b].y += v0.z * dreg[0].y + v0.w * dreg[1].y;
        acc[b].z += v0.w * dreg[0].z + w4.x * dreg[1].z;
        acc[b].w += w4.x * dreg[0].w + w4.y * dreg[1].w;

        // t=2 (shift 4): w4 itself
        acc[b].x += w4.x * dreg[2].x; acc[b].y += w4.y * dreg[2].y;
        acc[b].z += w4.z * dreg[2].z; acc[b].w += w4.w * dreg[2].w;

        // t=3..10 (shifts 8..1024): strip reads at tid*4 + 2^t
#pragma unroll
        for (int t = 3; t <= 10; ++t) {
            const float4 v = *(const float4*)(sp + (1 << t));
            acc[b].x += v.x * dreg[t].x; acc[b].y += v.y * dreg[t].y;
            acc[b].z += v.z * dreg[t].z; acc[b].w += v.w * dreg[t].w;
        }

        // t=11..15: the staged global loads
#pragma unroll
        for (int t = 11; t < 16; ++t) {
            const float4 v = vd[t - 11];
            acc[b].x += v.x * dreg[t].x; acc[b].y += v.y * dreg[t].y;
            acc[b].z += v.z * dreg[t].z; acc[b].w += v.w * dreg[t].w;
        }
    }

    // roll by 32768 == XOR top column bit; stores stay coalesced
#pragma unroll
    for (int b = 0; b < NB; ++b)
        *(float4*)(out + (size_t)(bg + b) * SLOTS + (j ^ 32768)) = acc[b];
}

extern "C" void kernel_launch(void* const* d_in, const int* in_sizes, int n_in,
                              void* d_out, int out_size, void* d_ws, size_t ws_size,
                              hipStream_t stream) {
    const float* x    = (const float*)d_in[0];   // (64, 65536) fp32
    const float* diag = (const float*)d_in[1];   // (16, 65536) fp32
    float* out        = (float*)d_out;           // (64, 65536) fp32
    // d_in[2] = stride (1), d_in[3] = reps (1) -- compile-time constants here.

    bsgs_kernel<<<dim3(1024), dim3(256), 0, stream>>>(x, diag, out);
}